// Round 3
// baseline (1064.361 us; speedup 1.0000x reference)
//
#include <hip/hip_runtime.h>
#include <stdint.h>

#define DEVI __device__ __forceinline__

typedef __attribute__((ext_vector_type(8))) short bf16x8;
typedef __attribute__((ext_vector_type(4))) float f32x4;
typedef unsigned short u16;
typedef unsigned int u32;

#define TT 2049           // T+1
#define BH 32             // B*H
#define MPAD 8320         // 65*128
#define MREAL 8196        // 4*2049
#define NQ 8192           // 4*N_QKV
#define KDIM 256
#define VTP 2112          // padded t-stride for V^T

DEVI u16 f2bf(float f) {
    union { float f; u32 u; } v; v.f = f;
    u32 r = v.u + 0x7FFF + ((v.u >> 16) & 1);
    return (u16)(r >> 16);
}
DEVI float bf2f(u16 h) {
    union { u32 u; float f; } v; v.u = ((u32)h) << 16;
    return v.f;
}

#define GLD16(src, lds) __builtin_amdgcn_global_load_lds( \
    (const __attribute__((address_space(1))) void*)(src), \
    (__attribute__((address_space(3))) void*)(lds), 16, 0, 0)

// ---------------- conversion kernels (x4 vectorized) ----------------
__global__ void k_conv_x0(const float* __restrict__ x, const float* __restrict__ wsink,
                          u16* __restrict__ x0b) {
    int idx = blockIdx.x * 256 + threadIdx.x;
    if (idx >= MPAD * 64) return;
    int m = idx >> 6, c = (idx & 63) << 2;
    f32x4 v = {0.f, 0.f, 0.f, 0.f};
    if (m < MREAL) {
        int b = m / TT, t = m - b * TT;
        const float* src = (t == 0) ? (wsink + c) : (x + ((size_t)((b << 11) + t - 1) << 8) + c);
        v = *(const f32x4*)src;
    }
    union { u16 h[4]; uint2 u2; } o;
#pragma unroll
    for (int i = 0; i < 4; ++i) o.h[i] = f2bf(v[i]);
    *(uint2*)(x0b + ((size_t)idx << 2)) = o.u2;
}

__global__ void k_conv_bf16(const float* __restrict__ s, u16* __restrict__ d, int n4) {
    int idx = blockIdx.x * 256 + threadIdx.x;
    if (idx >= n4) return;
    f32x4 v = *(const f32x4*)(s + ((size_t)idx << 2));
    union { u16 h[4]; uint2 u2; } o;
#pragma unroll
    for (int i = 0; i < 4; ++i) o.h[i] = f2bf(v[i]);
    *(uint2*)(d + ((size_t)idx << 2)) = o.u2;
}

// ---------------- GEMM1: qkvg = x0 @ Wqkvg^T, scatter epilogue ----------------
__global__ __launch_bounds__(256) void k_gemm_qkvg(const u16* __restrict__ A, const u16* __restrict__ Bm,
                                                   u16* __restrict__ Qb, u16* __restrict__ Kb,
                                                   u16* __restrict__ Vt, u16* __restrict__ Gb) {
    __shared__ __align__(16) u16 ldsA[128 * 64];
    __shared__ __align__(16) u16 ldsB[128 * 64];
    const int tid = threadIdx.x;
    const int l = tid & 63, w = tid >> 6;
    const int row0 = blockIdx.x * 128, col0 = blockIdx.y * 128;
    const int mbase = (w >> 1) * 64, nbase = (w & 1) * 64;
    f32x4 acc[4][4];
    const f32x4 zero = {0.f, 0.f, 0.f, 0.f};
#pragma unroll
    for (int i = 0; i < 4; ++i)
#pragma unroll
        for (int j = 0; j < 4; ++j) acc[i][j] = zero;

    for (int kt = 0; kt < KDIM; kt += 64) {
        __syncthreads();
#pragma unroll
        for (int it = 0; it < 4; ++it) {
            int lin = (it * 256 + tid) * 16;
            int r = lin >> 7;
            int cb = lin & 127;
            int scb = cb ^ ((r & 7) << 4);
            const char* sa = (const char*)(A + (size_t)(row0 + r) * KDIM + kt) + scb;
            const char* sb = (const char*)(Bm + (size_t)(col0 + r) * KDIM + kt) + scb;
            GLD16(sa, (char*)ldsA + it * 4096 + w * 1024);
            GLD16(sb, (char*)ldsB + it * 4096 + w * 1024);
        }
        __syncthreads();
#pragma unroll
        for (int kk = 0; kk < 64; kk += 32) {
            bf16x8 af[4], bfr[4];
            int cbyte = (kk + ((l >> 4) << 3)) * 2;
#pragma unroll
            for (int mi = 0; mi < 4; ++mi) {
                int rr = mbase + mi * 16 + (l & 15);
                af[mi] = *(const bf16x8*)((const char*)ldsA + ((rr * 128 + cbyte) ^ ((rr & 7) << 4)));
            }
#pragma unroll
            for (int ni = 0; ni < 4; ++ni) {
                int rr = nbase + ni * 16 + (l & 15);
                bfr[ni] = *(const bf16x8*)((const char*)ldsB + ((rr * 128 + cbyte) ^ ((rr & 7) << 4)));
            }
#pragma unroll
            for (int mi = 0; mi < 4; ++mi)
#pragma unroll
                for (int ni = 0; ni < 4; ++ni)
                    acc[mi][ni] = __builtin_amdgcn_mfma_f32_16x16x32_bf16(af[mi], bfr[ni], acc[mi][ni], 0, 0, 0);
        }
    }
#pragma unroll
    for (int mi = 0; mi < 4; ++mi)
#pragma unroll
        for (int ni = 0; ni < 4; ++ni)
#pragma unroll
            for (int r = 0; r < 4; ++r) {
                int grow = row0 + mbase + mi * 16 + ((l >> 4) << 2) + r;
                if (grow >= MREAL) continue;
                int gcol = col0 + nbase + ni * 16 + (l & 15);
                int b = grow / TT, t = grow - b * TT;
                int h = gcol >> 10, c = gcol & 1023;
                int ty = c >> 8, d = c & 255;
                int bh = b * 8 + h;
                u16 val = f2bf(acc[mi][ni][r]);
                if (ty == 0)      Qb[((size_t)(bh * TT + t) << 8) + d] = val;
                else if (ty == 1) Kb[((size_t)(bh * TT + t) << 8) + d] = val;
                else if (ty == 2) Vt[(size_t)(bh * 256 + d) * VTP + t] = val;
                else              Gb[((size_t)(bh * TT + t) << 8) + d] = val;
            }
}

// ---------------- RoPE + RMSNorm (in place on Q,K), one wave per row ----------------
// Q additionally pre-scaled by 1/16 (the attention score scale) so k_attn skips it.
__global__ void k_rope_rms(u16* __restrict__ Qb, u16* __restrict__ Kb,
                           const float* __restrict__ cosb, const float* __restrict__ sinb,
                           const float* __restrict__ tao) {
    int wid = blockIdx.x * 4 + (threadIdx.x >> 6);
    int l = threadIdx.x & 63;
    const int NROW = BH * TT;
    if (wid >= 2 * NROW) return;
    u16* buf = (wid < NROW) ? Qb : Kb;
    float tv = (wid < NROW) ? tao[0] * 0.0625f : tao[1];
    int r = (wid < NROW) ? wid : wid - NROW;
    int t = r % TT;
    size_t base = ((size_t)r) << 8;
    int dd = l * 2;
    float x1a = bf2f(buf[base + dd]),       x1b = bf2f(buf[base + dd + 1]);
    float x2a = bf2f(buf[base + dd + 128]), x2b = bf2f(buf[base + dd + 129]);
    float ca = cosb[t * 128 + dd], cb = cosb[t * 128 + dd + 1];
    float sa = sinb[t * 128 + dd], sb = sinb[t * 128 + dd + 1];
    float y1a = x1a * ca + x2a * sa;
    float y1b = x1b * cb + x2b * sb;
    float y2a = -x1a * sa + x2a * ca;
    float y2b = -x1b * sb + x2b * cb;
    float ss = y1a * y1a + y1b * y1b + y2a * y2a + y2b * y2b;
#pragma unroll
    for (int m = 1; m < 64; m <<= 1) ss += __shfl_xor(ss, m, 64);
    float scale = rsqrtf(ss * (1.0f / 256.0f) + 1.1920928955078125e-07f) * tv;
    buf[base + dd]       = f2bf(y1a * scale);
    buf[base + dd + 1]   = f2bf(y1b * scale);
    buf[base + dd + 128] = f2bf(y2a * scale);
    buf[base + dd + 129] = f2bf(y2b * scale);
}

// ---------------- flash attention, causal, 128 q-rows per block, 8 waves ----------------
// Single-buffered K+V in LDS (80KB total -> 2 blocks/CU, 4 waves/SIMD); cross-block
// wave overlap replaces the explicit double buffer. P round-trip XOR-swizzled.
// Defer-max (T13, THR=8) + setprio (T5) around MFMA clusters.
__global__ __launch_bounds__(512, 4) void k_attn(const u16* __restrict__ Qb, const u16* __restrict__ Kb,
                                                 const u16* __restrict__ Vt, const u16* __restrict__ Gb,
                                                 u16* __restrict__ Y) {
    __shared__ __align__(16) u16 Kt[64 * 256];      // [kv=64][d=256] swizzled, 32KB
    __shared__ __align__(16) u16 Vl[256 * 64];      // [d=256][kv=64] swizzled, 32KB
    __shared__ __align__(16) u16 Plds[8][16 * 64];  // per-wave P tile, swizzled, 16KB
    const int tid = threadIdx.x, l = tid & 63, w = tid >> 6;
    const int qt = 16 - blockIdx.x;        // heavy tiles first
    const int bh = blockIdx.y;
    const int b = bh >> 3, h = bh & 7;
    const int mq0 = qt * 128 + w * 16;
    const bool wactive = (mq0 <= 2048);
    const size_t qkbase = (size_t)bh * TT * 256;
    const size_t vrow0 = (size_t)bh * 256;

    bf16x8 aq[8];
    {
        int mq = mq0 + (l & 15); if (mq > 2048) mq = 2048;
        const u16* qp = Qb + qkbase + ((size_t)mq << 8) + ((l >> 4) << 3);
#pragma unroll
        for (int kk = 0; kk < 8; ++kk) aq[kk] = *(const bf16x8*)(qp + kk * 32);
    }
    f32x4 acc[16];
    const f32x4 zero = {0.f, 0.f, 0.f, 0.f};
#pragma unroll
    for (int i = 0; i < 16; ++i) acc[i] = zero;
    float mrun[4] = {-1e30f, -1e30f, -1e30f, -1e30f};
    float lrun[4] = {0.f, 0.f, 0.f, 0.f};

    int kmax = qt * 128 + 127; if (kmax > 2048) kmax = 2048;
    const int nkv = (kmax >> 6) + 1;

    for (int j = 0; j < nkv; ++j) {
        const int kv0 = j << 6;
        // ---- stage K+V tile (wave-uniform LDS dest, pre-swizzled global src) ----
#pragma unroll
        for (int it = 0; it < 4; ++it) {
            int lin = (it * 512 + tid) * 16;
            {   // K tile: rows of 512B
                int r = lin >> 9, cbyt = lin & 511;
                int scb = cbyt ^ ((r & 7) << 4);
                int krow = kv0 + r; if (krow > 2048) krow = 2048;
                GLD16((const char*)(Kb + qkbase + ((size_t)krow << 8)) + scb,
                      (char*)Kt + it * 8192 + w * 1024);
            }
            {   // V^T tile: rows of 128B
                int vr = lin >> 7, cb = lin & 127;
                int scb = cb ^ ((vr & 7) << 4);
                GLD16((const char*)(Vt + (vrow0 + vr) * VTP + kv0) + scb,
                      (char*)Vl + it * 8192 + w * 1024);
            }
        }
        __syncthreads();

        if (wactive && kv0 <= mq0) {
            f32x4 s[4];
#pragma unroll
            for (int nf = 0; nf < 4; ++nf) s[nf] = zero;
            __builtin_amdgcn_s_setprio(1);
#pragma unroll
            for (int kk = 0; kk < 8; ++kk) {
                int cbyte = kk * 64 + ((l >> 4) << 4);
#pragma unroll
                for (int nf = 0; nf < 4; ++nf) {
                    int rr = nf * 16 + (l & 15);
                    bf16x8 bk = *(const bf16x8*)((const char*)Kt + ((rr * 512 + cbyte) ^ ((rr & 7) << 4)));
                    s[nf] = __builtin_amdgcn_mfma_f32_16x16x32_bf16(aq[kk], bk, s[nf], 0, 0, 0);
                }
            }
            __builtin_amdgcn_s_setprio(0);
            const bool needmask = (kv0 + 63 > mq0);
            float p[4][4];
#pragma unroll
            for (int nf = 0; nf < 4; ++nf)
#pragma unroll
                for (int r = 0; r < 4; ++r) {
                    float sv = s[nf][r];
                    if (needmask) {
                        int kg = kv0 + nf * 16 + (l & 15);
                        int qg = mq0 + ((l >> 4) << 2) + r;
                        if (kg > qg) sv = -1e30f;
                    }
                    p[nf][r] = sv;
                }
#pragma unroll
            for (int r = 0; r < 4; ++r) {
                float vm = fmaxf(fmaxf(p[0][r], p[1][r]), fmaxf(p[2][r], p[3][r]));
#pragma unroll
                for (int m = 1; m < 16; m <<= 1) vm = fmaxf(vm, __shfl_xor(vm, m, 64));
                if (vm > mrun[r] + 8.f) {   // T13 defer-max: rescale only on real growth
                    float alpha = __expf(mrun[r] - vm);
                    mrun[r] = vm;
                    lrun[r] *= alpha;
#pragma unroll
                    for (int df = 0; df < 16; ++df) acc[df][r] *= alpha;
                }
                float rs = 0.f;
#pragma unroll
                for (int nf = 0; nf < 4; ++nf) {
                    float pv = __expf(p[nf][r] - mrun[r]);
                    p[nf][r] = pv;
                    rs += pv;
                }
#pragma unroll
                for (int m = 1; m < 16; m <<= 1) rs += __shfl_xor(rs, m, 64);
                lrun[r] += rs;
            }
            {   // P write, XOR-swizzled
                char* pwb = (char*)&Plds[w][0];
#pragma unroll
                for (int nf = 0; nf < 4; ++nf)
#pragma unroll
                    for (int r = 0; r < 4; ++r) {
                        int row = ((l >> 4) << 2) + r;
                        int byte = row * 128 + nf * 32 + (l & 15) * 2;
                        *(u16*)(pwb + (byte ^ ((row & 7) << 4))) = f2bf(p[nf][r]);
                    }
            }
            {   // P read (swizzled) + PV
                const char* prb = (const char*)&Plds[w][0];
                int row = l & 15;
                int b0 = row * 128 + ((l >> 4) << 4);
                bf16x8 ap0 = *(const bf16x8*)(prb + (b0 ^ ((row & 7) << 4)));
                bf16x8 ap1 = *(const bf16x8*)(prb + ((b0 + 64) ^ ((row & 7) << 4)));
                __builtin_amdgcn_s_setprio(1);
#pragma unroll
                for (int df = 0; df < 16; ++df) {
                    int vr = df * 16 + (l & 15);
                    int cbase = vr * 128 + ((l >> 4) << 4);
                    bf16x8 bv0 = *(const bf16x8*)((const char*)Vl + (cbase ^ ((vr & 7) << 4)));
                    bf16x8 bv1 = *(const bf16x8*)((const char*)Vl + ((cbase + 64) ^ ((vr & 7) << 4)));
                    acc[df] = __builtin_amdgcn_mfma_f32_16x16x32_bf16(ap0, bv0, acc[df], 0, 0, 0);
                    acc[df] = __builtin_amdgcn_mfma_f32_16x16x32_bf16(ap1, bv1, acc[df], 0, 0, 0);
                }
                __builtin_amdgcn_s_setprio(0);
            }
        }
        __syncthreads();
    }
#pragma unroll
    for (int r = 0; r < 4; ++r) {
        int mq = mq0 + ((l >> 4) << 2) + r;
        if (mq < 1 || mq > 2048) continue;
        float inv = 1.0f / lrun[r];
        const u16* gp = Gb + qkbase + ((size_t)mq << 8) + (l & 15);
        u16* yp = Y + ((size_t)(b * 2048 + mq - 1)) * 2048 + h * 256 + (l & 15);
#pragma unroll
        for (int df = 0; df < 16; ++df) {
            float g = bf2f(gp[df * 16]);
            float sg = 1.0f / (1.0f + __expf(-g));
            yp[df * 16] = f2bf(acc[df][r] * inv * sg);
        }
    }
}

// ---------------- GEMM3: out = Y @ Wout^T (BM=64, BN=128 -> 256 blocks) ----------------
__global__ __launch_bounds__(256) void k_gemm_out(const u16* __restrict__ A, const u16* __restrict__ Bm,
                                                  float* __restrict__ Cout) {
    __shared__ __align__(16) u16 ldsA[64 * 64];
    __shared__ __align__(16) u16 ldsB[128 * 64];
    const int tid = threadIdx.x;
    const int l = tid & 63, w = tid >> 6;
    const int row0 = blockIdx.x * 64, col0 = blockIdx.y * 128;
    const int mbase = (w >> 1) * 32, nbase = (w & 1) * 64;
    const int K2 = 2048;
    f32x4 acc[2][4];
    const f32x4 zero = {0.f, 0.f, 0.f, 0.f};
#pragma unroll
    for (int i = 0; i < 2; ++i)
#pragma unroll
        for (int j = 0; j < 4; ++j) acc[i][j] = zero;

    for (int kt = 0; kt < K2; kt += 64) {
        __syncthreads();
#pragma unroll
        for (int it = 0; it < 2; ++it) {
            int lin = (it * 256 + tid) * 16;
            int r = lin >> 7;
            int cb = lin & 127;
            int scb = cb ^ ((r & 7) << 4);
            const char* sa = (const char*)(A + (size_t)(row0 + r) * K2 + kt) + scb;
            GLD16(sa, (char*)ldsA + it * 4096 + w * 1024);
        }
#pragma unroll
        for (int it = 0; it < 4; ++it) {
            int lin = (it * 256 + tid) * 16;
            int r = lin >> 7;
            int cb = lin & 127;
            int scb = cb ^ ((r & 7) << 4);
            const char* sb = (const char*)(Bm + (size_t)(col0 + r) * K2 + kt) + scb;
            GLD16(sb, (char*)ldsB + it * 4096 + w * 1024);
        }
        __syncthreads();
#pragma unroll
        for (int kk = 0; kk < 64; kk += 32) {
            bf16x8 af[2], bfr[4];
            int cbyte = (kk + ((l >> 4) << 3)) * 2;
#pragma unroll
            for (int mi = 0; mi < 2; ++mi) {
                int rr = mbase + mi * 16 + (l & 15);
                af[mi] = *(const bf16x8*)((const char*)ldsA + ((rr * 128 + cbyte) ^ ((rr & 7) << 4)));
            }
#pragma unroll
            for (int ni = 0; ni < 4; ++ni) {
                int rr = nbase + ni * 16 + (l & 15);
                bfr[ni] = *(const bf16x8*)((const char*)ldsB + ((rr * 128 + cbyte) ^ ((rr & 7) << 4)));
            }
#pragma unroll
            for (int mi = 0; mi < 2; ++mi)
#pragma unroll
                for (int ni = 0; ni < 4; ++ni)
                    acc[mi][ni] = __builtin_amdgcn_mfma_f32_16x16x32_bf16(af[mi], bfr[ni], acc[mi][ni], 0, 0, 0);
        }
    }
#pragma unroll
    for (int mi = 0; mi < 2; ++mi)
#pragma unroll
        for (int ni = 0; ni < 4; ++ni)
#pragma unroll
            for (int r = 0; r < 4; ++r) {
                int grow = row0 + mbase + mi * 16 + ((l >> 4) << 2) + r;
                int gcol = col0 + nbase + ni * 16 + (l & 15);
                Cout[(size_t)grow * 256 + gcol] = acc[mi][ni][r];
            }
}

extern "C" void kernel_launch(void* const* d_in, const int* in_sizes, int n_in,
                              void* d_out, int out_size, void* d_ws, size_t ws_size,
                              hipStream_t stream) {
    const float* x     = (const float*)d_in[0];
    const float* cosb  = (const float*)d_in[1];
    const float* sinb  = (const float*)d_in[2];
    const float* wqkvg = (const float*)d_in[3];
    const float* wsink = (const float*)d_in[4];
    const float* wout  = (const float*)d_in[5];
    const float* tao   = (const float*)d_in[6];
    float* out = (float*)d_out;

    char* ws = (char*)d_ws;
    u16* x0b = (u16*)(ws + 0);            // 8320*256*2       = 4,259,840
    u16* wqb = (u16*)(ws + 4259840);      // 8192*256*2       = 4,194,304
    u16* wob = (u16*)(ws + 8454144);      // 256*2048*2       = 1,048,576
    u16* Qb  = (u16*)(ws + 9502720);      // 32*2049*256*2    = 33,570,816
    u16* Kb  = (u16*)(ws + 43073536);     // 33,570,816
    u16* Gb  = (u16*)(ws + 76644352);     // 33,570,816
    u16* Vt  = (u16*)(ws + 110215168);    // 32*256*2112*2    = 34,603,008
    u16* Yb  = (u16*)(ws + 144818176);    // 8192*2048*2      = 33,554,432
    // total 178,372,608 bytes

    k_conv_x0<<<dim3((MPAD * 64 + 255) / 256), 256, 0, stream>>>(x, wsink, x0b);
    k_conv_bf16<<<dim3((NQ * 64 + 255) / 256), 256, 0, stream>>>(wqkvg, wqb, NQ * 64);
    k_conv_bf16<<<dim3((256 * 512 + 255) / 256), 256, 0, stream>>>(wout, wob, 256 * 512);
    k_gemm_qkvg<<<dim3(65, 64), 256, 0, stream>>>(x0b, wqb, Qb, Kb, Vt, Gb);
    k_rope_rms<<<dim3((2 * BH * TT + 3) / 4), 256, 0, stream>>>(Qb, Kb, cosb, sinb, tao);
    k_attn<<<dim3(17, 32), 512, 0, stream>>>(Qb, Kb, Vt, Gb, Yb);
    k_gemm_out<<<dim3(128, 2), 256, 0, stream>>>(Yb, wob, out);
}

// Round 4
// 413.888 us; speedup vs baseline: 2.5716x; 2.5716x over previous
//
#include <hip/hip_runtime.h>
#include <stdint.h>

#define DEVI __device__ __forceinline__

typedef __attribute__((ext_vector_type(8))) short bf16x8;
typedef __attribute__((ext_vector_type(4))) float f32x4;
typedef unsigned short u16;
typedef unsigned int u32;

#define TT 2049           // T+1
#define BH 32             // B*H
#define MPAD 8320         // 65*128
#define MREAL 8196        // 4*2049
#define NQ 8192           // 4*N_QKV
#define KDIM 256
#define VTP 2112          // padded t-stride for V^T

DEVI u16 f2bf(float f) {
    union { float f; u32 u; } v; v.f = f;
    u32 r = v.u + 0x7FFF + ((v.u >> 16) & 1);
    return (u16)(r >> 16);
}
DEVI float bf2f(u16 h) {
    union { u32 u; float f; } v; v.u = ((u32)h) << 16;
    return v.f;
}

#define GLD16(src, lds) __builtin_amdgcn_global_load_lds( \
    (const __attribute__((address_space(1))) void*)(src), \
    (__attribute__((address_space(3))) void*)(lds), 16, 0, 0)

// ---------------- conversion kernels (x4 vectorized) ----------------
__global__ void k_conv_x0(const float* __restrict__ x, const float* __restrict__ wsink,
                          u16* __restrict__ x0b) {
    int idx = blockIdx.x * 256 + threadIdx.x;
    if (idx >= MPAD * 64) return;
    int m = idx >> 6, c = (idx & 63) << 2;
    f32x4 v = {0.f, 0.f, 0.f, 0.f};
    if (m < MREAL) {
        int b = m / TT, t = m - b * TT;
        const float* src = (t == 0) ? (wsink + c) : (x + ((size_t)((b << 11) + t - 1) << 8) + c);
        v = *(const f32x4*)src;
    }
    union { u16 h[4]; uint2 u2; } o;
#pragma unroll
    for (int i = 0; i < 4; ++i) o.h[i] = f2bf(v[i]);
    *(uint2*)(x0b + ((size_t)idx << 2)) = o.u2;
}

__global__ void k_conv_bf16(const float* __restrict__ s, u16* __restrict__ d, int n4) {
    int idx = blockIdx.x * 256 + threadIdx.x;
    if (idx >= n4) return;
    f32x4 v = *(const f32x4*)(s + ((size_t)idx << 2));
    union { u16 h[4]; uint2 u2; } o;
#pragma unroll
    for (int i = 0; i < 4; ++i) o.h[i] = f2bf(v[i]);
    *(uint2*)(d + ((size_t)idx << 2)) = o.u2;
}

// ---------------- GEMM1: qkvg = x0 @ Wqkvg^T, scatter epilogue ----------------
__global__ __launch_bounds__(256) void k_gemm_qkvg(const u16* __restrict__ A, const u16* __restrict__ Bm,
                                                   u16* __restrict__ Qb, u16* __restrict__ Kb,
                                                   u16* __restrict__ Vt, u16* __restrict__ Gb) {
    __shared__ __align__(16) u16 ldsA[128 * 64];
    __shared__ __align__(16) u16 ldsB[128 * 64];
    const int tid = threadIdx.x;
    const int l = tid & 63, w = tid >> 6;
    const int row0 = blockIdx.x * 128, col0 = blockIdx.y * 128;
    const int mbase = (w >> 1) * 64, nbase = (w & 1) * 64;
    f32x4 acc[4][4];
    const f32x4 zero = {0.f, 0.f, 0.f, 0.f};
#pragma unroll
    for (int i = 0; i < 4; ++i)
#pragma unroll
        for (int j = 0; j < 4; ++j) acc[i][j] = zero;

    for (int kt = 0; kt < KDIM; kt += 64) {
        __syncthreads();
#pragma unroll
        for (int it = 0; it < 4; ++it) {
            int lin = (it * 256 + tid) * 16;
            int r = lin >> 7;
            int cb = lin & 127;
            int scb = cb ^ ((r & 7) << 4);
            const char* sa = (const char*)(A + (size_t)(row0 + r) * KDIM + kt) + scb;
            const char* sb = (const char*)(Bm + (size_t)(col0 + r) * KDIM + kt) + scb;
            GLD16(sa, (char*)ldsA + it * 4096 + w * 1024);
            GLD16(sb, (char*)ldsB + it * 4096 + w * 1024);
        }
        __syncthreads();
#pragma unroll
        for (int kk = 0; kk < 64; kk += 32) {
            bf16x8 af[4], bfr[4];
            int cbyte = (kk + ((l >> 4) << 3)) * 2;
#pragma unroll
            for (int mi = 0; mi < 4; ++mi) {
                int rr = mbase + mi * 16 + (l & 15);
                af[mi] = *(const bf16x8*)((const char*)ldsA + ((rr * 128 + cbyte) ^ ((rr & 7) << 4)));
            }
#pragma unroll
            for (int ni = 0; ni < 4; ++ni) {
                int rr = nbase + ni * 16 + (l & 15);
                bfr[ni] = *(const bf16x8*)((const char*)ldsB + ((rr * 128 + cbyte) ^ ((rr & 7) << 4)));
            }
#pragma unroll
            for (int mi = 0; mi < 4; ++mi)
#pragma unroll
                for (int ni = 0; ni < 4; ++ni)
                    acc[mi][ni] = __builtin_amdgcn_mfma_f32_16x16x32_bf16(af[mi], bfr[ni], acc[mi][ni], 0, 0, 0);
        }
    }
#pragma unroll
    for (int mi = 0; mi < 4; ++mi)
#pragma unroll
        for (int ni = 0; ni < 4; ++ni)
#pragma unroll
            for (int r = 0; r < 4; ++r) {
                int grow = row0 + mbase + mi * 16 + ((l >> 4) << 2) + r;
                if (grow >= MREAL) continue;
                int gcol = col0 + nbase + ni * 16 + (l & 15);
                int b = grow / TT, t = grow - b * TT;
                int h = gcol >> 10, c = gcol & 1023;
                int ty = c >> 8, d = c & 255;
                int bh = b * 8 + h;
                u16 val = f2bf(acc[mi][ni][r]);
                if (ty == 0)      Qb[((size_t)(bh * TT + t) << 8) + d] = val;
                else if (ty == 1) Kb[((size_t)(bh * TT + t) << 8) + d] = val;
                else if (ty == 2) Vt[(size_t)(bh * 256 + d) * VTP + t] = val;
                else              Gb[((size_t)(bh * TT + t) << 8) + d] = val;
            }
}

// ---------------- RoPE + RMSNorm (in place on Q,K), one wave per row ----------------
// Q additionally pre-scaled by 1/16 (the attention score scale) so k_attn skips it.
__global__ void k_rope_rms(u16* __restrict__ Qb, u16* __restrict__ Kb,
                           const float* __restrict__ cosb, const float* __restrict__ sinb,
                           const float* __restrict__ tao) {
    int wid = blockIdx.x * 4 + (threadIdx.x >> 6);
    int l = threadIdx.x & 63;
    const int NROW = BH * TT;
    if (wid >= 2 * NROW) return;
    u16* buf = (wid < NROW) ? Qb : Kb;
    float tv = (wid < NROW) ? tao[0] * 0.0625f : tao[1];
    int r = (wid < NROW) ? wid : wid - NROW;
    int t = r % TT;
    size_t base = ((size_t)r) << 8;
    int dd = l * 2;
    float x1a = bf2f(buf[base + dd]),       x1b = bf2f(buf[base + dd + 1]);
    float x2a = bf2f(buf[base + dd + 128]), x2b = bf2f(buf[base + dd + 129]);
    float ca = cosb[t * 128 + dd], cb = cosb[t * 128 + dd + 1];
    float sa = sinb[t * 128 + dd], sb = sinb[t * 128 + dd + 1];
    float y1a = x1a * ca + x2a * sa;
    float y1b = x1b * cb + x2b * sb;
    float y2a = -x1a * sa + x2a * ca;
    float y2b = -x1b * sb + x2b * cb;
    float ss = y1a * y1a + y1b * y1b + y2a * y2a + y2b * y2b;
#pragma unroll
    for (int m = 1; m < 64; m <<= 1) ss += __shfl_xor(ss, m, 64);
    float scale = rsqrtf(ss * (1.0f / 256.0f) + 1.1920928955078125e-07f) * tv;
    buf[base + dd]       = f2bf(y1a * scale);
    buf[base + dd + 1]   = f2bf(y1b * scale);
    buf[base + dd + 128] = f2bf(y2a * scale);
    buf[base + dd + 129] = f2bf(y2b * scale);
}

// ---------------- flash attention, causal, 128 q-rows per block, 8 waves ----------------
// Double-buffered K+V in LDS (round-2 structure; 1 block/CU is structural given the
// 64-reg accumulator -> pipeline within the block, not across blocks).
// P round-trip XOR-swizzled; defer-max (T13); setprio (T5); Q pre-scaled by 1/16.
__global__ __launch_bounds__(512) void k_attn(const u16* __restrict__ Qb, const u16* __restrict__ Kb,
                                              const u16* __restrict__ Vt, const u16* __restrict__ Gb,
                                              u16* __restrict__ Y) {
    __shared__ __align__(16) u16 Kt[2][64 * 256];   // [kv=64][d=256] swizzled, 32KB each
    __shared__ __align__(16) u16 Vl[2][256 * 64];   // [d=256][kv=64] swizzled, 32KB each
    __shared__ __align__(16) u16 Plds[8][16 * 64];  // per-wave P tile, swizzled
    const int tid = threadIdx.x, l = tid & 63, w = tid >> 6;
    const int qt = 16 - blockIdx.x;        // heavy tiles first
    const int bh = blockIdx.y;
    const int b = bh >> 3, h = bh & 7;
    const int mq0 = qt * 128 + w * 16;
    const bool wactive = (mq0 <= 2048);
    const size_t qkbase = (size_t)bh * TT * 256;
    const size_t vrow0 = (size_t)bh * 256;

    bf16x8 aq[8];
    {
        int mq = mq0 + (l & 15); if (mq > 2048) mq = 2048;
        const u16* qp = Qb + qkbase + ((size_t)mq << 8) + ((l >> 4) << 3);
#pragma unroll
        for (int kk = 0; kk < 8; ++kk) aq[kk] = *(const bf16x8*)(qp + kk * 32);
    }
    f32x4 acc[16];
    const f32x4 zero = {0.f, 0.f, 0.f, 0.f};
#pragma unroll
    for (int i = 0; i < 16; ++i) acc[i] = zero;
    float mrun[4] = {-1e30f, -1e30f, -1e30f, -1e30f};
    float lrun[4] = {0.f, 0.f, 0.f, 0.f};

    int kmax = qt * 128 + 127; if (kmax > 2048) kmax = 2048;
    const int nkv = (kmax >> 6) + 1;

    auto STAGE = [&](int j, int bufi) {
        const int kv0 = j << 6;
#pragma unroll
        for (int it = 0; it < 4; ++it) {
            int lin = (it * 512 + tid) * 16;
            {   // K tile: rows of 512B
                int r = lin >> 9, cbyt = lin & 511;
                int scb = cbyt ^ ((r & 7) << 4);
                int krow = kv0 + r; if (krow > 2048) krow = 2048;
                GLD16((const char*)(Kb + qkbase + ((size_t)krow << 8)) + scb,
                      (char*)&Kt[bufi][0] + it * 8192 + w * 1024);
            }
            {   // V^T tile: rows of 128B
                int vr = lin >> 7, cb = lin & 127;
                int scb = cb ^ ((vr & 7) << 4);
                GLD16((const char*)(Vt + (vrow0 + vr) * VTP + kv0) + scb,
                      (char*)&Vl[bufi][0] + it * 8192 + w * 1024);
            }
        }
    };

    STAGE(0, 0);
    __syncthreads();
    int buf = 0;

    for (int j = 0; j < nkv; ++j) {
        const int kv0 = j << 6;
        if (j + 1 < nkv) STAGE(j + 1, buf ^ 1);

        if (wactive && kv0 <= mq0) {
            f32x4 s[4];
#pragma unroll
            for (int nf = 0; nf < 4; ++nf) s[nf] = zero;
            __builtin_amdgcn_s_setprio(1);
#pragma unroll
            for (int kk = 0; kk < 8; ++kk) {
                int cbyte = kk * 64 + ((l >> 4) << 4);
#pragma unroll
                for (int nf = 0; nf < 4; ++nf) {
                    int rr = nf * 16 + (l & 15);
                    bf16x8 bk = *(const bf16x8*)((const char*)&Kt[buf][0] + ((rr * 512 + cbyte) ^ ((rr & 7) << 4)));
                    s[nf] = __builtin_amdgcn_mfma_f32_16x16x32_bf16(aq[kk], bk, s[nf], 0, 0, 0);
                }
            }
            __builtin_amdgcn_s_setprio(0);
            const bool needmask = (kv0 + 63 > mq0);
            float p[4][4];
#pragma unroll
            for (int nf = 0; nf < 4; ++nf)
#pragma unroll
                for (int r = 0; r < 4; ++r) {
                    float sv = s[nf][r];
                    if (needmask) {
                        int kg = kv0 + nf * 16 + (l & 15);
                        int qg = mq0 + ((l >> 4) << 2) + r;
                        if (kg > qg) sv = -1e30f;
                    }
                    p[nf][r] = sv;
                }
#pragma unroll
            for (int r = 0; r < 4; ++r) {
                float vm = fmaxf(fmaxf(p[0][r], p[1][r]), fmaxf(p[2][r], p[3][r]));
#pragma unroll
                for (int m = 1; m < 16; m <<= 1) vm = fmaxf(vm, __shfl_xor(vm, m, 64));
                if (vm > mrun[r] + 8.f) {   // T13 defer-max
                    float alpha = __expf(mrun[r] - vm);
                    mrun[r] = vm;
                    lrun[r] *= alpha;
#pragma unroll
                    for (int df = 0; df < 16; ++df) acc[df][r] *= alpha;
                }
                float rs = 0.f;
#pragma unroll
                for (int nf = 0; nf < 4; ++nf) {
                    float pv = __expf(p[nf][r] - mrun[r]);
                    p[nf][r] = pv;
                    rs += pv;
                }
#pragma unroll
                for (int m = 1; m < 16; m <<= 1) rs += __shfl_xor(rs, m, 64);
                lrun[r] += rs;
            }
            {   // P write, XOR-swizzled
                char* pwb = (char*)&Plds[w][0];
#pragma unroll
                for (int nf = 0; nf < 4; ++nf)
#pragma unroll
                    for (int r = 0; r < 4; ++r) {
                        int row = ((l >> 4) << 2) + r;
                        int byte = row * 128 + nf * 32 + (l & 15) * 2;
                        *(u16*)(pwb + (byte ^ ((row & 7) << 4))) = f2bf(p[nf][r]);
                    }
            }
            {   // P read (swizzled) + PV
                const char* prb = (const char*)&Plds[w][0];
                int row = l & 15;
                int b0 = row * 128 + ((l >> 4) << 4);
                bf16x8 ap0 = *(const bf16x8*)(prb + (b0 ^ ((row & 7) << 4)));
                bf16x8 ap1 = *(const bf16x8*)(prb + ((b0 + 64) ^ ((row & 7) << 4)));
                __builtin_amdgcn_s_setprio(1);
#pragma unroll
                for (int df = 0; df < 16; ++df) {
                    int vr = df * 16 + (l & 15);
                    int cbase = vr * 128 + ((l >> 4) << 4);
                    bf16x8 bv0 = *(const bf16x8*)((const char*)&Vl[buf][0] + (cbase ^ ((vr & 7) << 4)));
                    bf16x8 bv1 = *(const bf16x8*)((const char*)&Vl[buf][0] + ((cbase + 64) ^ ((vr & 7) << 4)));
                    acc[df] = __builtin_amdgcn_mfma_f32_16x16x32_bf16(ap0, bv0, acc[df], 0, 0, 0);
                    acc[df] = __builtin_amdgcn_mfma_f32_16x16x32_bf16(ap1, bv1, acc[df], 0, 0, 0);
                }
                __builtin_amdgcn_s_setprio(0);
            }
        }
        __syncthreads();
        buf ^= 1;
    }
#pragma unroll
    for (int r = 0; r < 4; ++r) {
        int mq = mq0 + ((l >> 4) << 2) + r;
        if (mq < 1 || mq > 2048) continue;
        float inv = 1.0f / lrun[r];
        const u16* gp = Gb + qkbase + ((size_t)mq << 8) + (l & 15);
        u16* yp = Y + ((size_t)(b * 2048 + mq - 1)) * 2048 + h * 256 + (l & 15);
#pragma unroll
        for (int df = 0; df < 16; ++df) {
            float g = bf2f(gp[df * 16]);
            float sg = 1.0f / (1.0f + __expf(-g));
            yp[df * 16] = f2bf(acc[df][r] * inv * sg);
        }
    }
}

// ---------------- GEMM3: out = Y @ Wout^T (BM=64, BN=128 -> 256 blocks) ----------------
__global__ __launch_bounds__(256) void k_gemm_out(const u16* __restrict__ A, const u16* __restrict__ Bm,
                                                  float* __restrict__ Cout) {
    __shared__ __align__(16) u16 ldsA[64 * 64];
    __shared__ __align__(16) u16 ldsB[128 * 64];
    const int tid = threadIdx.x;
    const int l = tid & 63, w = tid >> 6;
    const int row0 = blockIdx.x * 64, col0 = blockIdx.y * 128;
    const int mbase = (w >> 1) * 32, nbase = (w & 1) * 64;
    const int K2 = 2048;
    f32x4 acc[2][4];
    const f32x4 zero = {0.f, 0.f, 0.f, 0.f};
#pragma unroll
    for (int i = 0; i < 2; ++i)
#pragma unroll
        for (int j = 0; j < 4; ++j) acc[i][j] = zero;

    for (int kt = 0; kt < K2; kt += 64) {
        __syncthreads();
#pragma unroll
        for (int it = 0; it < 2; ++it) {
            int lin = (it * 256 + tid) * 16;
            int r = lin >> 7;
            int cb = lin & 127;
            int scb = cb ^ ((r & 7) << 4);
            const char* sa = (const char*)(A + (size_t)(row0 + r) * K2 + kt) + scb;
            GLD16(sa, (char*)ldsA + it * 4096 + w * 1024);
        }
#pragma unroll
        for (int it = 0; it < 4; ++it) {
            int lin = (it * 256 + tid) * 16;
            int r = lin >> 7;
            int cb = lin & 127;
            int scb = cb ^ ((r & 7) << 4);
            const char* sb = (const char*)(Bm + (size_t)(col0 + r) * K2 + kt) + scb;
            GLD16(sb, (char*)ldsB + it * 4096 + w * 1024);
        }
        __syncthreads();
#pragma unroll
        for (int kk = 0; kk < 64; kk += 32) {
            bf16x8 af[2], bfr[4];
            int cbyte = (kk + ((l >> 4) << 3)) * 2;
#pragma unroll
            for (int mi = 0; mi < 2; ++mi) {
                int rr = mbase + mi * 16 + (l & 15);
                af[mi] = *(const bf16x8*)((const char*)ldsA + ((rr * 128 + cbyte) ^ ((rr & 7) << 4)));
            }
#pragma unroll
            for (int ni = 0; ni < 4; ++ni) {
                int rr = nbase + ni * 16 + (l & 15);
                bfr[ni] = *(const bf16x8*)((const char*)ldsB + ((rr * 128 + cbyte) ^ ((rr & 7) << 4)));
            }
#pragma unroll
            for (int mi = 0; mi < 2; ++mi)
#pragma unroll
                for (int ni = 0; ni < 4; ++ni)
                    acc[mi][ni] = __builtin_amdgcn_mfma_f32_16x16x32_bf16(af[mi], bfr[ni], acc[mi][ni], 0, 0, 0);
        }
    }
#pragma unroll
    for (int mi = 0; mi < 2; ++mi)
#pragma unroll
        for (int ni = 0; ni < 4; ++ni)
#pragma unroll
            for (int r = 0; r < 4; ++r) {
                int grow = row0 + mbase + mi * 16 + ((l >> 4) << 2) + r;
                int gcol = col0 + nbase + ni * 16 + (l & 15);
                Cout[(size_t)grow * 256 + gcol] = acc[mi][ni][r];
            }
}

extern "C" void kernel_launch(void* const* d_in, const int* in_sizes, int n_in,
                              void* d_out, int out_size, void* d_ws, size_t ws_size,
                              hipStream_t stream) {
    const float* x     = (const float*)d_in[0];
    const float* cosb  = (const float*)d_in[1];
    const float* sinb  = (const float*)d_in[2];
    const float* wqkvg = (const float*)d_in[3];
    const float* wsink = (const float*)d_in[4];
    const float* wout  = (const float*)d_in[5];
    const float* tao   = (const float*)d_in[6];
    float* out = (float*)d_out;

    char* ws = (char*)d_ws;
    u16* x0b = (u16*)(ws + 0);            // 8320*256*2       = 4,259,840
    u16* wqb = (u16*)(ws + 4259840);      // 8192*256*2       = 4,194,304
    u16* wob = (u16*)(ws + 8454144);      // 256*2048*2       = 1,048,576
    u16* Qb  = (u16*)(ws + 9502720);      // 32*2049*256*2    = 33,570,816
    u16* Kb  = (u16*)(ws + 43073536);     // 33,570,816
    u16* Gb  = (u16*)(ws + 76644352);     // 33,570,816
    u16* Vt  = (u16*)(ws + 110215168);    // 32*256*2112*2    = 34,603,008
    u16* Yb  = (u16*)(ws + 144818176);    // 8192*2048*2      = 33,554,432
    // total 178,372,608 bytes

    k_conv_x0<<<dim3((MPAD * 64 + 255) / 256), 256, 0, stream>>>(x, wsink, x0b);
    k_conv_bf16<<<dim3((NQ * 64 + 255) / 256), 256, 0, stream>>>(wqkvg, wqb, NQ * 64);
    k_conv_bf16<<<dim3((256 * 512 + 255) / 256), 256, 0, stream>>>(wout, wob, 256 * 512);
    k_gemm_qkvg<<<dim3(65, 64), 256, 0, stream>>>(x0b, wqb, Qb, Kb, Vt, Gb);
    k_rope_rms<<<dim3((2 * BH * TT + 3) / 4), 256, 0, stream>>>(Qb, Kb, cosb, sinb, tao);
    k_attn<<<dim3(17, 32), 512, 0, stream>>>(Qb, Kb, Vt, Gb, Yb);
    k_gemm_out<<<dim3(128, 2), 256, 0, stream>>>(Yb, wob, out);
}

// Round 5
// 298.978 us; speedup vs baseline: 3.5600x; 1.3843x over previous
//
#include <hip/hip_runtime.h>
#include <stdint.h>

#define DEVI __device__ __forceinline__

typedef __attribute__((ext_vector_type(8))) short bf16x8;
typedef __attribute__((ext_vector_type(4))) float f32x4;
typedef unsigned short u16;
typedef unsigned int u32;

#define TT 2049           // T+1
#define BH 32             // B*H
#define MPAD 8320         // 65*128
#define MREAL 8196        // 4*2049
#define NQ 8192           // 4*N_QKV
#define KDIM 256
#define VTP 2112          // padded t-stride for V^T

DEVI u16 f2bf(float f) {
    union { float f; u32 u; } v; v.f = f;
    u32 r = v.u + 0x7FFF + ((v.u >> 16) & 1);
    return (u16)(r >> 16);
}
DEVI float bf2f(u16 h) {
    union { u32 u; float f; } v; v.u = ((u32)h) << 16;
    return v.f;
}

#define GLD16(src, lds) __builtin_amdgcn_global_load_lds( \
    (const __attribute__((address_space(1))) void*)(src), \
    (__attribute__((address_space(3))) void*)(lds), 16, 0, 0)

// ---------------- conversion kernels (x4 vectorized) ----------------
__global__ void k_conv_x0(const float* __restrict__ x, const float* __restrict__ wsink,
                          u16* __restrict__ x0b) {
    int idx = blockIdx.x * 256 + threadIdx.x;
    if (idx >= MPAD * 64) return;
    int m = idx >> 6, c = (idx & 63) << 2;
    f32x4 v = {0.f, 0.f, 0.f, 0.f};
    if (m < MREAL) {
        int b = m / TT, t = m - b * TT;
        const float* src = (t == 0) ? (wsink + c) : (x + ((size_t)((b << 11) + t - 1) << 8) + c);
        v = *(const f32x4*)src;
    }
    union { u16 h[4]; uint2 u2; } o;
#pragma unroll
    for (int i = 0; i < 4; ++i) o.h[i] = f2bf(v[i]);
    *(uint2*)(x0b + ((size_t)idx << 2)) = o.u2;
}

__global__ void k_conv_bf16(const float* __restrict__ s, u16* __restrict__ d, int n4) {
    int idx = blockIdx.x * 256 + threadIdx.x;
    if (idx >= n4) return;
    f32x4 v = *(const f32x4*)(s + ((size_t)idx << 2));
    union { u16 h[4]; uint2 u2; } o;
#pragma unroll
    for (int i = 0; i < 4; ++i) o.h[i] = f2bf(v[i]);
    *(uint2*)(d + ((size_t)idx << 2)) = o.u2;
}

// ---------------- GEMM1: qkvg = x0 @ Wqkvg^T, scatter epilogue ----------------
__global__ __launch_bounds__(256) void k_gemm_qkvg(const u16* __restrict__ A, const u16* __restrict__ Bm,
                                                   u16* __restrict__ Qb, u16* __restrict__ Kb,
                                                   u16* __restrict__ Vt, u16* __restrict__ Gb) {
    __shared__ __align__(16) u16 ldsA[128 * 64];
    __shared__ __align__(16) u16 ldsB[128 * 64];
    const int tid = threadIdx.x;
    const int l = tid & 63, w = tid >> 6;
    const int row0 = blockIdx.x * 128, col0 = blockIdx.y * 128;
    const int mbase = (w >> 1) * 64, nbase = (w & 1) * 64;
    f32x4 acc[4][4];
    const f32x4 zero = {0.f, 0.f, 0.f, 0.f};
#pragma unroll
    for (int i = 0; i < 4; ++i)
#pragma unroll
        for (int j = 0; j < 4; ++j) acc[i][j] = zero;

    for (int kt = 0; kt < KDIM; kt += 64) {
        __syncthreads();
#pragma unroll
        for (int it = 0; it < 4; ++it) {
            int lin = (it * 256 + tid) * 16;
            int r = lin >> 7;
            int cb = lin & 127;
            int scb = cb ^ ((r & 7) << 4);
            const char* sa = (const char*)(A + (size_t)(row0 + r) * KDIM + kt) + scb;
            const char* sb = (const char*)(Bm + (size_t)(col0 + r) * KDIM + kt) + scb;
            GLD16(sa, (char*)ldsA + it * 4096 + w * 1024);
            GLD16(sb, (char*)ldsB + it * 4096 + w * 1024);
        }
        __syncthreads();
#pragma unroll
        for (int kk = 0; kk < 64; kk += 32) {
            bf16x8 af[4], bfr[4];
            int cbyte = (kk + ((l >> 4) << 3)) * 2;
#pragma unroll
            for (int mi = 0; mi < 4; ++mi) {
                int rr = mbase + mi * 16 + (l & 15);
                af[mi] = *(const bf16x8*)((const char*)ldsA + ((rr * 128 + cbyte) ^ ((rr & 7) << 4)));
            }
#pragma unroll
            for (int ni = 0; ni < 4; ++ni) {
                int rr = nbase + ni * 16 + (l & 15);
                bfr[ni] = *(const bf16x8*)((const char*)ldsB + ((rr * 128 + cbyte) ^ ((rr & 7) << 4)));
            }
#pragma unroll
            for (int mi = 0; mi < 4; ++mi)
#pragma unroll
                for (int ni = 0; ni < 4; ++ni)
                    acc[mi][ni] = __builtin_amdgcn_mfma_f32_16x16x32_bf16(af[mi], bfr[ni], acc[mi][ni], 0, 0, 0);
        }
    }
#pragma unroll
    for (int mi = 0; mi < 4; ++mi)
#pragma unroll
        for (int ni = 0; ni < 4; ++ni)
#pragma unroll
            for (int r = 0; r < 4; ++r) {
                int grow = row0 + mbase + mi * 16 + ((l >> 4) << 2) + r;
                if (grow >= MREAL) continue;
                int gcol = col0 + nbase + ni * 16 + (l & 15);
                int b = grow / TT, t = grow - b * TT;
                int h = gcol >> 10, c = gcol & 1023;
                int ty = c >> 8, d = c & 255;
                int bh = b * 8 + h;
                u16 val = f2bf(acc[mi][ni][r]);
                if (ty == 0)      Qb[((size_t)(bh * TT + t) << 8) + d] = val;
                else if (ty == 1) Kb[((size_t)(bh * TT + t) << 8) + d] = val;
                else if (ty == 2) Vt[(size_t)(bh * 256 + d) * VTP + t] = val;
                else              Gb[((size_t)(bh * TT + t) << 8) + d] = val;
            }
}

// ---------------- RoPE + RMSNorm (in place on Q,K), one wave per row ----------------
// Q additionally pre-scaled by 1/16 (the attention score scale) so k_attn skips it.
__global__ void k_rope_rms(u16* __restrict__ Qb, u16* __restrict__ Kb,
                           const float* __restrict__ cosb, const float* __restrict__ sinb,
                           const float* __restrict__ tao) {
    int wid = blockIdx.x * 4 + (threadIdx.x >> 6);
    int l = threadIdx.x & 63;
    const int NROW = BH * TT;
    if (wid >= 2 * NROW) return;
    u16* buf = (wid < NROW) ? Qb : Kb;
    float tv = (wid < NROW) ? tao[0] * 0.0625f : tao[1];
    int r = (wid < NROW) ? wid : wid - NROW;
    int t = r % TT;
    size_t base = ((size_t)r) << 8;
    int dd = l * 2;
    float x1a = bf2f(buf[base + dd]),       x1b = bf2f(buf[base + dd + 1]);
    float x2a = bf2f(buf[base + dd + 128]), x2b = bf2f(buf[base + dd + 129]);
    float ca = cosb[t * 128 + dd], cb = cosb[t * 128 + dd + 1];
    float sa = sinb[t * 128 + dd], sb = sinb[t * 128 + dd + 1];
    float y1a = x1a * ca + x2a * sa;
    float y1b = x1b * cb + x2b * sb;
    float y2a = -x1a * sa + x2a * ca;
    float y2b = -x1b * sb + x2b * cb;
    float ss = y1a * y1a + y1b * y1b + y2a * y2a + y2b * y2b;
#pragma unroll
    for (int m = 1; m < 64; m <<= 1) ss += __shfl_xor(ss, m, 64);
    float scale = rsqrtf(ss * (1.0f / 256.0f) + 1.1920928955078125e-07f) * tv;
    buf[base + dd]       = f2bf(y1a * scale);
    buf[base + dd + 1]   = f2bf(y1b * scale);
    buf[base + dd + 128] = f2bf(y2a * scale);
    buf[base + dd + 129] = f2bf(y2b * scale);
}

// ---------------- flash attention, causal, 128 q-rows per block, 8 waves ----------------
// FIXED-SHIFT softmax: |s| <= 16*tao0*tao1 (rmsnorm bound) -> p = exp(s - C), no
// online max/sum tracking at all. Row-sums accumulate via a V ones-column (acc[16]).
// Double-buffered K+V; P round-trip XOR-swizzled; setprio; bh pinned to one XCD.
__global__ __launch_bounds__(512) void k_attn(const u16* __restrict__ Qb, const u16* __restrict__ Kb,
                                              const u16* __restrict__ Vt, const u16* __restrict__ Gb,
                                              const float* __restrict__ tao,
                                              u16* __restrict__ Y) {
    __shared__ __align__(16) u16 Kt[2][64 * 256];   // 32KB each
    __shared__ __align__(16) u16 Vl[2][272 * 64];   // 34KB each (rows 256..271 = ones-pad)
    __shared__ __align__(16) u16 Plds[8][16 * 64];  // per-wave P tile, swizzled
    const int tid = threadIdx.x, l = tid & 63, w = tid >> 6;
    const int qt = 16 - (blockIdx.x >> 5);          // heavy tiles first
    const int bh = blockIdx.x & 31;                 // id%8 == bh%8 -> bh pinned to XCD
    const int b = bh >> 3, h = bh & 7;
    const int mq0 = qt * 128 + w * 16;
    const bool wactive = (mq0 <= 2048);
    const size_t qkbase = (size_t)bh * TT * 256;
    const size_t vrow0 = (size_t)bh * 256;
    const float Cs = tao[0] * tao[1] * 16.0f;       // score upper bound

    bf16x8 aq[8];
    {
        int mq = mq0 + (l & 15); if (mq > 2048) mq = 2048;
        const u16* qp = Qb + qkbase + ((size_t)mq << 8) + ((l >> 4) << 3);
#pragma unroll
        for (int kk = 0; kk < 8; ++kk) aq[kk] = *(const bf16x8*)(qp + kk * 32);
    }
    f32x4 acc[17];
    const f32x4 zero = {0.f, 0.f, 0.f, 0.f};
#pragma unroll
    for (int i = 0; i < 17; ++i) acc[i] = zero;

    int kmax = qt * 128 + 127; if (kmax > 2048) kmax = 2048;
    const int nkv = (kmax >> 6) + 1;

    auto STAGE = [&](int j, int bufi) {
        const int kv0 = j << 6;
#pragma unroll
        for (int it = 0; it < 4; ++it) {
            int lin = (it * 512 + tid) * 16;
            {   // K tile: rows of 512B
                int r = lin >> 9, cbyt = lin & 511;
                int scb = cbyt ^ ((r & 7) << 4);
                int krow = kv0 + r; if (krow > 2048) krow = 2048;
                GLD16((const char*)(Kb + qkbase + ((size_t)krow << 8)) + scb,
                      (char*)&Kt[bufi][0] + it * 8192 + w * 1024);
            }
            {   // V^T tile: rows of 128B
                int vr = lin >> 7, cb = lin & 127;
                int scb = cb ^ ((vr & 7) << 4);
                GLD16((const char*)(Vt + (vrow0 + vr) * VTP + kv0) + scb,
                      (char*)&Vl[bufi][0] + it * 8192 + w * 1024);
            }
        }
    };

    // ones-pad rows 256..271 of both V buffers (row 256 = 1.0, rest 0), written once
    for (int i = tid; i < 2048; i += 512) {
        int bufi = i >> 10;
        int rr = 256 + ((i >> 6) & 15);
        int cc = i & 63;
        int byte = rr * 128 + cc * 2;
        *(u16*)((char*)&Vl[bufi][0] + (byte ^ ((rr & 7) << 4))) = (rr == 256) ? (u16)0x3F80 : (u16)0;
    }
    STAGE(0, 0);
    __syncthreads();
    int buf = 0;

    for (int j = 0; j < nkv; ++j) {
        const int kv0 = j << 6;
        if (j + 1 < nkv) STAGE(j + 1, buf ^ 1);

        if (wactive && kv0 <= mq0) {
            f32x4 s[4];
#pragma unroll
            for (int nf = 0; nf < 4; ++nf) s[nf] = zero;
            __builtin_amdgcn_s_setprio(1);
#pragma unroll
            for (int kk = 0; kk < 8; ++kk) {
                int cbyte = kk * 64 + ((l >> 4) << 4);
#pragma unroll
                for (int nf = 0; nf < 4; ++nf) {
                    int rr = nf * 16 + (l & 15);
                    bf16x8 bk = *(const bf16x8*)((const char*)&Kt[buf][0] + ((rr * 512 + cbyte) ^ ((rr & 7) << 4)));
                    s[nf] = __builtin_amdgcn_mfma_f32_16x16x32_bf16(aq[kk], bk, s[nf], 0, 0, 0);
                }
            }
            __builtin_amdgcn_s_setprio(0);
            const bool needmask = (kv0 + 63 > mq0);
            {   // p = exp(s - C), masked -> 0; write P XOR-swizzled
                char* pwb = (char*)&Plds[w][0];
#pragma unroll
                for (int nf = 0; nf < 4; ++nf)
#pragma unroll
                    for (int r = 0; r < 4; ++r) {
                        float sv = s[nf][r];
                        if (needmask) {
                            int kg = kv0 + nf * 16 + (l & 15);
                            int qg = mq0 + ((l >> 4) << 2) + r;
                            if (kg > qg) sv = -1e30f;
                        }
                        float pv = __expf(sv - Cs);
                        int row = ((l >> 4) << 2) + r;
                        int byte = row * 128 + nf * 32 + (l & 15) * 2;
                        *(u16*)(pwb + (byte ^ ((row & 7) << 4))) = f2bf(pv);
                    }
            }
            {   // P read (swizzled) + PV (df=16 is the ones-column -> row sums)
                const char* prb = (const char*)&Plds[w][0];
                int row = l & 15;
                int b0 = row * 128 + ((l >> 4) << 4);
                bf16x8 ap0 = *(const bf16x8*)(prb + (b0 ^ ((row & 7) << 4)));
                bf16x8 ap1 = *(const bf16x8*)(prb + ((b0 + 64) ^ ((row & 7) << 4)));
                __builtin_amdgcn_s_setprio(1);
#pragma unroll
                for (int df = 0; df < 17; ++df) {
                    int vr = df * 16 + (l & 15);
                    int cbase = vr * 128 + ((l >> 4) << 4);
                    bf16x8 bv0 = *(const bf16x8*)((const char*)&Vl[buf][0] + (cbase ^ ((vr & 7) << 4)));
                    bf16x8 bv1 = *(const bf16x8*)((const char*)&Vl[buf][0] + ((cbase + 64) ^ ((vr & 7) << 4)));
                    acc[df] = __builtin_amdgcn_mfma_f32_16x16x32_bf16(ap0, bv0, acc[df], 0, 0, 0);
                    acc[df] = __builtin_amdgcn_mfma_f32_16x16x32_bf16(ap1, bv1, acc[df], 0, 0, 0);
                }
                __builtin_amdgcn_s_setprio(0);
            }
        }
        __syncthreads();
        buf ^= 1;
    }
#pragma unroll
    for (int r = 0; r < 4; ++r) {
        int mq = mq0 + ((l >> 4) << 2) + r;
        if (mq < 1 || mq > 2048) continue;
        float rsum = __shfl(acc[16][r], (l & 48), 64);   // sum lives in lane&15==0 of each group
        float inv = 1.0f / rsum;
        const u16* gp = Gb + qkbase + ((size_t)mq << 8) + (l & 15);
        u16* yp = Y + ((size_t)(b * 2048 + mq - 1)) * 2048 + h * 256 + (l & 15);
#pragma unroll
        for (int df = 0; df < 16; ++df) {
            float g = bf2f(gp[df * 16]);
            float sg = 1.0f / (1.0f + __expf(-g));
            yp[df * 16] = f2bf(acc[df][r] * inv * sg);
        }
    }
}

// ---------------- GEMM3: out = Y @ Wout^T (BM=64, BN=128 -> 256 blocks) ----------------
__global__ __launch_bounds__(256) void k_gemm_out(const u16* __restrict__ A, const u16* __restrict__ Bm,
                                                  float* __restrict__ Cout) {
    __shared__ __align__(16) u16 ldsA[64 * 64];
    __shared__ __align__(16) u16 ldsB[128 * 64];
    const int tid = threadIdx.x;
    const int l = tid & 63, w = tid >> 6;
    const int row0 = blockIdx.x * 64, col0 = blockIdx.y * 128;
    const int mbase = (w >> 1) * 32, nbase = (w & 1) * 64;
    const int K2 = 2048;
    f32x4 acc[2][4];
    const f32x4 zero = {0.f, 0.f, 0.f, 0.f};
#pragma unroll
    for (int i = 0; i < 2; ++i)
#pragma unroll
        for (int j = 0; j < 4; ++j) acc[i][j] = zero;

    for (int kt = 0; kt < K2; kt += 64) {
        __syncthreads();
#pragma unroll
        for (int it = 0; it < 2; ++it) {
            int lin = (it * 256 + tid) * 16;
            int r = lin >> 7;
            int cb = lin & 127;
            int scb = cb ^ ((r & 7) << 4);
            const char* sa = (const char*)(A + (size_t)(row0 + r) * K2 + kt) + scb;
            GLD16(sa, (char*)ldsA + it * 4096 + w * 1024);
        }
#pragma unroll
        for (int it = 0; it < 4; ++it) {
            int lin = (it * 256 + tid) * 16;
            int r = lin >> 7;
            int cb = lin & 127;
            int scb = cb ^ ((r & 7) << 4);
            const char* sb = (const char*)(Bm + (size_t)(col0 + r) * K2 + kt) + scb;
            GLD16(sb, (char*)ldsB + it * 4096 + w * 1024);
        }
        __syncthreads();
#pragma unroll
        for (int kk = 0; kk < 64; kk += 32) {
            bf16x8 af[2], bfr[4];
            int cbyte = (kk + ((l >> 4) << 3)) * 2;
#pragma unroll
            for (int mi = 0; mi < 2; ++mi) {
                int rr = mbase + mi * 16 + (l & 15);
                af[mi] = *(const bf16x8*)((const char*)ldsA + ((rr * 128 + cbyte) ^ ((rr & 7) << 4)));
            }
#pragma unroll
            for (int ni = 0; ni < 4; ++ni) {
                int rr = nbase + ni * 16 + (l & 15);
                bfr[ni] = *(const bf16x8*)((const char*)ldsB + ((rr * 128 + cbyte) ^ ((rr & 7) << 4)));
            }
#pragma unroll
            for (int mi = 0; mi < 2; ++mi)
#pragma unroll
                for (int ni = 0; ni < 4; ++ni)
                    acc[mi][ni] = __builtin_amdgcn_mfma_f32_16x16x32_bf16(af[mi], bfr[ni], acc[mi][ni], 0, 0, 0);
        }
    }
#pragma unroll
    for (int mi = 0; mi < 2; ++mi)
#pragma unroll
        for (int ni = 0; ni < 4; ++ni)
#pragma unroll
            for (int r = 0; r < 4; ++r) {
                int grow = row0 + mbase + mi * 16 + ((l >> 4) << 2) + r;
                int gcol = col0 + nbase + ni * 16 + (l & 15);
                Cout[(size_t)grow * 256 + gcol] = acc[mi][ni][r];
            }
}

extern "C" void kernel_launch(void* const* d_in, const int* in_sizes, int n_in,
                              void* d_out, int out_size, void* d_ws, size_t ws_size,
                              hipStream_t stream) {
    const float* x     = (const float*)d_in[0];
    const float* cosb  = (const float*)d_in[1];
    const float* sinb  = (const float*)d_in[2];
    const float* wqkvg = (const float*)d_in[3];
    const float* wsink = (const float*)d_in[4];
    const float* wout  = (const float*)d_in[5];
    const float* tao   = (const float*)d_in[6];
    float* out = (float*)d_out;

    char* ws = (char*)d_ws;
    u16* x0b = (u16*)(ws + 0);            // 8320*256*2       = 4,259,840
    u16* wqb = (u16*)(ws + 4259840);      // 8192*256*2       = 4,194,304
    u16* wob = (u16*)(ws + 8454144);      // 256*2048*2       = 1,048,576
    u16* Qb  = (u16*)(ws + 9502720);      // 32*2049*256*2    = 33,570,816
    u16* Kb  = (u16*)(ws + 43073536);     // 33,570,816
    u16* Gb  = (u16*)(ws + 76644352);     // 33,570,816
    u16* Vt  = (u16*)(ws + 110215168);    // 32*256*2112*2    = 34,603,008
    u16* Yb  = (u16*)(ws + 144818176);    // 8192*2048*2      = 33,554,432
    // total 178,372,608 bytes

    k_conv_x0<<<dim3((MPAD * 64 + 255) / 256), 256, 0, stream>>>(x, wsink, x0b);
    k_conv_bf16<<<dim3((NQ * 64 + 255) / 256), 256, 0, stream>>>(wqkvg, wqb, NQ * 64);
    k_conv_bf16<<<dim3((256 * 512 + 255) / 256), 256, 0, stream>>>(wout, wob, 256 * 512);
    k_gemm_qkvg<<<dim3(65, 64), 256, 0, stream>>>(x0b, wqb, Qb, Kb, Vt, Gb);
    k_rope_rms<<<dim3((2 * BH * TT + 3) / 4), 256, 0, stream>>>(Qb, Kb, cosb, sinb, tao);
    k_attn<<<dim3(17 * 32), 512, 0, stream>>>(Qb, Kb, Vt, Gb, tao, Yb);
    k_gemm_out<<<dim3(128, 2), 256, 0, stream>>>(Yb, wob, out);
}

// Round 6
// 298.465 us; speedup vs baseline: 3.5661x; 1.0017x over previous
//
#include <hip/hip_runtime.h>
#include <stdint.h>

#define DEVI __device__ __forceinline__

typedef __attribute__((ext_vector_type(8))) short bf16x8;
typedef __attribute__((ext_vector_type(4))) float f32x4;
typedef unsigned short u16;
typedef unsigned int u32;

#define TT 2049           // T+1
#define BH 32             // B*H
#define MPAD 8320         // 65*128
#define MREAL 8196        // 4*2049
#define NQ 8192           // 4*N_QKV
#define KDIM 256
#define VTP 2112          // padded t-stride for V^T

DEVI u16 f2bf(float f) {
    union { float f; u32 u; } v; v.f = f;
    u32 r = v.u + 0x7FFF + ((v.u >> 16) & 1);
    return (u16)(r >> 16);
}
DEVI float bf2f(u16 h) {
    union { u32 u; float f; } v; v.u = ((u32)h) << 16;
    return v.f;
}

#define GLD16(src, lds) __builtin_amdgcn_global_load_lds( \
    (const __attribute__((address_space(1))) void*)(src), \
    (__attribute__((address_space(3))) void*)(lds), 16, 0, 0)

// ---------------- conversion kernels (x4 vectorized) ----------------
__global__ void k_conv_x0(const float* __restrict__ x, const float* __restrict__ wsink,
                          u16* __restrict__ x0b) {
    int idx = blockIdx.x * 256 + threadIdx.x;
    if (idx >= MPAD * 64) return;
    int m = idx >> 6, c = (idx & 63) << 2;
    f32x4 v = {0.f, 0.f, 0.f, 0.f};
    if (m < MREAL) {
        int b = m / TT, t = m - b * TT;
        const float* src = (t == 0) ? (wsink + c) : (x + ((size_t)((b << 11) + t - 1) << 8) + c);
        v = *(const f32x4*)src;
    }
    union { u16 h[4]; uint2 u2; } o;
#pragma unroll
    for (int i = 0; i < 4; ++i) o.h[i] = f2bf(v[i]);
    *(uint2*)(x0b + ((size_t)idx << 2)) = o.u2;
}

__global__ void k_conv_bf16(const float* __restrict__ s, u16* __restrict__ d, int n4) {
    int idx = blockIdx.x * 256 + threadIdx.x;
    if (idx >= n4) return;
    f32x4 v = *(const f32x4*)(s + ((size_t)idx << 2));
    union { u16 h[4]; uint2 u2; } o;
#pragma unroll
    for (int i = 0; i < 4; ++i) o.h[i] = f2bf(v[i]);
    *(uint2*)(d + ((size_t)idx << 2)) = o.u2;
}

// ---------------- GEMM1: qkvg = x0 @ Wqkvg^T, scatter epilogue ----------------
__global__ __launch_bounds__(256) void k_gemm_qkvg(const u16* __restrict__ A, const u16* __restrict__ Bm,
                                                   u16* __restrict__ Qb, u16* __restrict__ Kb,
                                                   u16* __restrict__ Vt, u16* __restrict__ Gb) {
    __shared__ __align__(16) u16 ldsA[128 * 64];
    __shared__ __align__(16) u16 ldsB[128 * 64];
    const int tid = threadIdx.x;
    const int l = tid & 63, w = tid >> 6;
    const int row0 = blockIdx.x * 128, col0 = blockIdx.y * 128;
    const int mbase = (w >> 1) * 64, nbase = (w & 1) * 64;
    f32x4 acc[4][4];
    const f32x4 zero = {0.f, 0.f, 0.f, 0.f};
#pragma unroll
    for (int i = 0; i < 4; ++i)
#pragma unroll
        for (int j = 0; j < 4; ++j) acc[i][j] = zero;

    for (int kt = 0; kt < KDIM; kt += 64) {
        __syncthreads();
#pragma unroll
        for (int it = 0; it < 4; ++it) {
            int lin = (it * 256 + tid) * 16;
            int r = lin >> 7;
            int cb = lin & 127;
            int scb = cb ^ ((r & 7) << 4);
            const char* sa = (const char*)(A + (size_t)(row0 + r) * KDIM + kt) + scb;
            const char* sb = (const char*)(Bm + (size_t)(col0 + r) * KDIM + kt) + scb;
            GLD16(sa, (char*)ldsA + it * 4096 + w * 1024);
            GLD16(sb, (char*)ldsB + it * 4096 + w * 1024);
        }
        __syncthreads();
#pragma unroll
        for (int kk = 0; kk < 64; kk += 32) {
            bf16x8 af[4], bfr[4];
            int cbyte = (kk + ((l >> 4) << 3)) * 2;
#pragma unroll
            for (int mi = 0; mi < 4; ++mi) {
                int rr = mbase + mi * 16 + (l & 15);
                af[mi] = *(const bf16x8*)((const char*)ldsA + ((rr * 128 + cbyte) ^ ((rr & 7) << 4)));
            }
#pragma unroll
            for (int ni = 0; ni < 4; ++ni) {
                int rr = nbase + ni * 16 + (l & 15);
                bfr[ni] = *(const bf16x8*)((const char*)ldsB + ((rr * 128 + cbyte) ^ ((rr & 7) << 4)));
            }
#pragma unroll
            for (int mi = 0; mi < 4; ++mi)
#pragma unroll
                for (int ni = 0; ni < 4; ++ni)
                    acc[mi][ni] = __builtin_amdgcn_mfma_f32_16x16x32_bf16(af[mi], bfr[ni], acc[mi][ni], 0, 0, 0);
        }
    }
#pragma unroll
    for (int mi = 0; mi < 4; ++mi)
#pragma unroll
        for (int ni = 0; ni < 4; ++ni)
#pragma unroll
            for (int r = 0; r < 4; ++r) {
                int grow = row0 + mbase + mi * 16 + ((l >> 4) << 2) + r;
                if (grow >= MREAL) continue;
                int gcol = col0 + nbase + ni * 16 + (l & 15);
                int b = grow / TT, t = grow - b * TT;
                int h = gcol >> 10, c = gcol & 1023;
                int ty = c >> 8, d = c & 255;
                int bh = b * 8 + h;
                u16 val = f2bf(acc[mi][ni][r]);
                if (ty == 0)      Qb[((size_t)(bh * TT + t) << 8) + d] = val;
                else if (ty == 1) Kb[((size_t)(bh * TT + t) << 8) + d] = val;
                else if (ty == 2) Vt[(size_t)(bh * 256 + d) * VTP + t] = val;
                else              Gb[((size_t)(bh * TT + t) << 8) + d] = val;
            }
}

// ---------------- RoPE + RMSNorm (in place on Q,K), one wave per row ----------------
// Q additionally pre-scaled by 1/16 (the attention score scale) so k_attn skips it.
__global__ void k_rope_rms(u16* __restrict__ Qb, u16* __restrict__ Kb,
                           const float* __restrict__ cosb, const float* __restrict__ sinb,
                           const float* __restrict__ tao) {
    int wid = blockIdx.x * 4 + (threadIdx.x >> 6);
    int l = threadIdx.x & 63;
    const int NROW = BH * TT;
    if (wid >= 2 * NROW) return;
    u16* buf = (wid < NROW) ? Qb : Kb;
    float tv = (wid < NROW) ? tao[0] * 0.0625f : tao[1];
    int r = (wid < NROW) ? wid : wid - NROW;
    int t = r % TT;
    size_t base = ((size_t)r) << 8;
    int dd = l * 2;
    float x1a = bf2f(buf[base + dd]),       x1b = bf2f(buf[base + dd + 1]);
    float x2a = bf2f(buf[base + dd + 128]), x2b = bf2f(buf[base + dd + 129]);
    float ca = cosb[t * 128 + dd], cb = cosb[t * 128 + dd + 1];
    float sa = sinb[t * 128 + dd], sb = sinb[t * 128 + dd + 1];
    float y1a = x1a * ca + x2a * sa;
    float y1b = x1b * cb + x2b * sb;
    float y2a = -x1a * sa + x2a * ca;
    float y2b = -x1b * sb + x2b * cb;
    float ss = y1a * y1a + y1b * y1b + y2a * y2a + y2b * y2b;
#pragma unroll
    for (int m = 1; m < 64; m <<= 1) ss += __shfl_xor(ss, m, 64);
    float scale = rsqrtf(ss * (1.0f / 256.0f) + 1.1920928955078125e-07f) * tv;
    buf[base + dd]       = f2bf(y1a * scale);
    buf[base + dd + 1]   = f2bf(y1b * scale);
    buf[base + dd + 128] = f2bf(y2a * scale);
    buf[base + dd + 129] = f2bf(y2b * scale);
}

// ---------------- flash attention, causal, 128 q-rows per block, 8 waves ----------------
// Fixed-shift softmax (no online tracking); row-sums via register ones-operand MFMA.
// Single-buffered K+V+P = 80KB LDS exactly -> 2 blocks/CU; cross-block overlap is the
// pipeline (m114). Only q-rows 1..2048 computed (row 0 dropped by reference) -> 512
// blocks = 2 per CU exactly. bh pinned to one XCD (blockIdx%8 == bh%8).
__global__ __launch_bounds__(512) void k_attn(const u16* __restrict__ Qb, const u16* __restrict__ Kb,
                                              const u16* __restrict__ Vt, const u16* __restrict__ Gb,
                                              const float* __restrict__ tao,
                                              u16* __restrict__ Y) {
    __shared__ __align__(16) u16 Kt[64 * 256];      // 32KB
    __shared__ __align__(16) u16 Vl[256 * 64];      // 32KB
    __shared__ __align__(16) u16 Plds[8][16 * 64];  // 16KB; total 80KB
    const int tid = threadIdx.x, l = tid & 63, w = tid >> 6;
    const int qt = 15 - (blockIdx.x >> 5);          // heavy tiles first
    const int bh = blockIdx.x & 31;                 // pinned to XCD bh%8
    const int b = bh >> 3, h = bh & 7;
    const int mq0 = qt * 128 + w * 16 + 1;          // q-rows 1..2048
    const size_t qkbase = (size_t)bh * TT * 256;
    const size_t vrow0 = (size_t)bh * 256;
    const float Cs = tao[0] * tao[1] * 16.0f;       // score upper bound (rmsnorm)

    bf16x8 aq[8];
    {
        int mq = mq0 + (l & 15);                    // <= 2048 always
        const u16* qp = Qb + qkbase + ((size_t)mq << 8) + ((l >> 4) << 3);
#pragma unroll
        for (int kk = 0; kk < 8; ++kk) aq[kk] = *(const bf16x8*)(qp + kk * 32);
    }
    bf16x8 vone;
#pragma unroll
    for (int i = 0; i < 8; ++i) vone[i] = (short)0x3F80;   // bf16 1.0
    f32x4 acc[16], accs;
    const f32x4 zero = {0.f, 0.f, 0.f, 0.f};
#pragma unroll
    for (int i = 0; i < 16; ++i) acc[i] = zero;
    accs = zero;

    const int nkv = 2 * qt + 3;

    for (int j = 0; j < nkv; ++j) {
        const int kv0 = j << 6;
        // ---- stage K+V tile (single buffer; prev compute done at loop-bottom barrier) ----
#pragma unroll
        for (int it = 0; it < 4; ++it) {
            int lin = (it * 512 + tid) * 16;
            {   // K tile: rows of 512B
                int r = lin >> 9, cbyt = lin & 511;
                int scb = cbyt ^ ((r & 7) << 4);
                int krow = kv0 + r; if (krow > 2048) krow = 2048;
                GLD16((const char*)(Kb + qkbase + ((size_t)krow << 8)) + scb,
                      (char*)Kt + it * 8192 + w * 1024);
            }
            {   // V^T tile: rows of 128B
                int vr = lin >> 7, cb = lin & 127;
                int scb = cb ^ ((vr & 7) << 4);
                GLD16((const char*)(Vt + (vrow0 + vr) * VTP + kv0) + scb,
                      (char*)Vl + it * 8192 + w * 1024);
            }
        }
        __syncthreads();

        if (kv0 <= mq0 + 15) {
            f32x4 s[4];
#pragma unroll
            for (int nf = 0; nf < 4; ++nf) s[nf] = zero;
            __builtin_amdgcn_s_setprio(1);
#pragma unroll
            for (int kk = 0; kk < 8; ++kk) {
                int cbyte = kk * 64 + ((l >> 4) << 4);
#pragma unroll
                for (int nf = 0; nf < 4; ++nf) {
                    int rr = nf * 16 + (l & 15);
                    bf16x8 bk = *(const bf16x8*)((const char*)Kt + ((rr * 512 + cbyte) ^ ((rr & 7) << 4)));
                    s[nf] = __builtin_amdgcn_mfma_f32_16x16x32_bf16(aq[kk], bk, s[nf], 0, 0, 0);
                }
            }
            __builtin_amdgcn_s_setprio(0);
            const bool needmask = (kv0 + 63 > mq0);
            {   // p = exp(s - C), masked -> 0; write P XOR-swizzled
                char* pwb = (char*)&Plds[w][0];
#pragma unroll
                for (int nf = 0; nf < 4; ++nf)
#pragma unroll
                    for (int r = 0; r < 4; ++r) {
                        float sv = s[nf][r];
                        if (needmask) {
                            int kg = kv0 + nf * 16 + (l & 15);
                            int qg = mq0 + ((l >> 4) << 2) + r;
                            if (kg > qg) sv = -1e30f;
                        }
                        float pv = __expf(sv - Cs);
                        int row = ((l >> 4) << 2) + r;
                        int byte = row * 128 + nf * 32 + (l & 15) * 2;
                        *(u16*)(pwb + (byte ^ ((row & 7) << 4))) = f2bf(pv);
                    }
            }
            {   // P read (swizzled) + PV; ones-operand MFMA accumulates row sums
                const char* prb = (const char*)&Plds[w][0];
                int row = l & 15;
                int b0 = row * 128 + ((l >> 4) << 4);
                bf16x8 ap0 = *(const bf16x8*)(prb + (b0 ^ ((row & 7) << 4)));
                bf16x8 ap1 = *(const bf16x8*)(prb + ((b0 + 64) ^ ((row & 7) << 4)));
                __builtin_amdgcn_s_setprio(1);
#pragma unroll
                for (int df = 0; df < 16; ++df) {
                    int vr = df * 16 + (l & 15);
                    int cbase = vr * 128 + ((l >> 4) << 4);
                    bf16x8 bv0 = *(const bf16x8*)((const char*)Vl + (cbase ^ ((vr & 7) << 4)));
                    bf16x8 bv1 = *(const bf16x8*)((const char*)Vl + ((cbase + 64) ^ ((vr & 7) << 4)));
                    acc[df] = __builtin_amdgcn_mfma_f32_16x16x32_bf16(ap0, bv0, acc[df], 0, 0, 0);
                    acc[df] = __builtin_amdgcn_mfma_f32_16x16x32_bf16(ap1, bv1, acc[df], 0, 0, 0);
                }
                accs = __builtin_amdgcn_mfma_f32_16x16x32_bf16(ap0, vone, accs, 0, 0, 0);
                accs = __builtin_amdgcn_mfma_f32_16x16x32_bf16(ap1, vone, accs, 0, 0, 0);
                __builtin_amdgcn_s_setprio(0);
            }
        }
        __syncthreads();
    }
#pragma unroll
    for (int r = 0; r < 4; ++r) {
        int mq = mq0 + ((l >> 4) << 2) + r;         // 1..2048 always
        float inv = 1.0f / accs[r];                  // every lane holds its row sum
        const u16* gp = Gb + qkbase + ((size_t)mq << 8) + (l & 15);
        u16* yp = Y + ((size_t)(b * 2048 + mq - 1)) * 2048 + h * 256 + (l & 15);
#pragma unroll
        for (int df = 0; df < 16; ++df) {
            float g = bf2f(gp[df * 16]);
            float sg = 1.0f / (1.0f + __expf(-g));
            yp[df * 16] = f2bf(acc[df][r] * inv * sg);
        }
    }
}

// ---------------- GEMM3: out = Y @ Wout^T (BM=64, BN=128 -> 256 blocks) ----------------
__global__ __launch_bounds__(256) void k_gemm_out(const u16* __restrict__ A, const u16* __restrict__ Bm,
                                                  float* __restrict__ Cout) {
    __shared__ __align__(16) u16 ldsA[64 * 64];
    __shared__ __align__(16) u16 ldsB[128 * 64];
    const int tid = threadIdx.x;
    const int l = tid & 63, w = tid >> 6;
    const int row0 = blockIdx.x * 64, col0 = blockIdx.y * 128;
    const int mbase = (w >> 1) * 32, nbase = (w & 1) * 64;
    const int K2 = 2048;
    f32x4 acc[2][4];
    const f32x4 zero = {0.f, 0.f, 0.f, 0.f};
#pragma unroll
    for (int i = 0; i < 2; ++i)
#pragma unroll
        for (int j = 0; j < 4; ++j) acc[i][j] = zero;

    for (int kt = 0; kt < K2; kt += 64) {
        __syncthreads();
#pragma unroll
        for (int it = 0; it < 2; ++it) {
            int lin = (it * 256 + tid) * 16;
            int r = lin >> 7;
            int cb = lin & 127;
            int scb = cb ^ ((r & 7) << 4);
            const char* sa = (const char*)(A + (size_t)(row0 + r) * K2 + kt) + scb;
            GLD16(sa, (char*)ldsA + it * 4096 + w * 1024);
        }
#pragma unroll
        for (int it = 0; it < 4; ++it) {
            int lin = (it * 256 + tid) * 16;
            int r = lin >> 7;
            int cb = lin & 127;
            int scb = cb ^ ((r & 7) << 4);
            const char* sb = (const char*)(Bm + (size_t)(col0 + r) * K2 + kt) + scb;
            GLD16(sb, (char*)ldsB + it * 4096 + w * 1024);
        }
        __syncthreads();
#pragma unroll
        for (int kk = 0; kk < 64; kk += 32) {
            bf16x8 af[2], bfr[4];
            int cbyte = (kk + ((l >> 4) << 3)) * 2;
#pragma unroll
            for (int mi = 0; mi < 2; ++mi) {
                int rr = mbase + mi * 16 + (l & 15);
                af[mi] = *(const bf16x8*)((const char*)ldsA + ((rr * 128 + cbyte) ^ ((rr & 7) << 4)));
            }
#pragma unroll
            for (int ni = 0; ni < 4; ++ni) {
                int rr = nbase + ni * 16 + (l & 15);
                bfr[ni] = *(const bf16x8*)((const char*)ldsB + ((rr * 128 + cbyte) ^ ((rr & 7) << 4)));
            }
#pragma unroll
            for (int mi = 0; mi < 2; ++mi)
#pragma unroll
                for (int ni = 0; ni < 4; ++ni)
                    acc[mi][ni] = __builtin_amdgcn_mfma_f32_16x16x32_bf16(af[mi], bfr[ni], acc[mi][ni], 0, 0, 0);
        }
    }
#pragma unroll
    for (int mi = 0; mi < 2; ++mi)
#pragma unroll
        for (int ni = 0; ni < 4; ++ni)
#pragma unroll
            for (int r = 0; r < 4; ++r) {
                int grow = row0 + mbase + mi * 16 + ((l >> 4) << 2) + r;
                int gcol = col0 + nbase + ni * 16 + (l & 15);
                Cout[(size_t)grow * 256 + gcol] = acc[mi][ni][r];
            }
}

extern "C" void kernel_launch(void* const* d_in, const int* in_sizes, int n_in,
                              void* d_out, int out_size, void* d_ws, size_t ws_size,
                              hipStream_t stream) {
    const float* x     = (const float*)d_in[0];
    const float* cosb  = (const float*)d_in[1];
    const float* sinb  = (const float*)d_in[2];
    const float* wqkvg = (const float*)d_in[3];
    const float* wsink = (const float*)d_in[4];
    const float* wout  = (const float*)d_in[5];
    const float* tao   = (const float*)d_in[6];
    float* out = (float*)d_out;

    char* ws = (char*)d_ws;
    u16* x0b = (u16*)(ws + 0);            // 8320*256*2       = 4,259,840
    u16* wqb = (u16*)(ws + 4259840);      // 8192*256*2       = 4,194,304
    u16* wob = (u16*)(ws + 8454144);      // 256*2048*2       = 1,048,576
    u16* Qb  = (u16*)(ws + 9502720);      // 32*2049*256*2    = 33,570,816
    u16* Kb  = (u16*)(ws + 43073536);     // 33,570,816
    u16* Gb  = (u16*)(ws + 76644352);     // 33,570,816
    u16* Vt  = (u16*)(ws + 110215168);    // 32*256*2112*2    = 34,603,008
    u16* Yb  = (u16*)(ws + 144818176);    // 8192*2048*2      = 33,554,432
    // total 178,372,608 bytes

    k_conv_x0<<<dim3((MPAD * 64 + 255) / 256), 256, 0, stream>>>(x, wsink, x0b);
    k_conv_bf16<<<dim3((NQ * 64 + 255) / 256), 256, 0, stream>>>(wqkvg, wqb, NQ * 64);
    k_conv_bf16<<<dim3((256 * 512 + 255) / 256), 256, 0, stream>>>(wout, wob, 256 * 512);
    k_gemm_qkvg<<<dim3(65, 64), 256, 0, stream>>>(x0b, wqb, Qb, Kb, Vt, Gb);
    k_rope_rms<<<dim3((2 * BH * TT + 3) / 4), 256, 0, stream>>>(Qb, Kb, cosb, sinb, tao);
    k_attn<<<dim3(16 * 32), 512, 0, stream>>>(Qb, Kb, Vt, Gb, tao, Yb);
    k_gemm_out<<<dim3(128, 2), 256, 0, stream>>>(Yb, wob, out);
}